// Round 15
// baseline (170.133 us; speedup 1.0000x reference)
//
#include <hip/hip_runtime.h>
#include <hip/hip_bf16.h>
#include <stdint.h>

// Problem constants
#define B_   4
#define T_   2048
#define H_   16
#define MTOT (B_ * T_)          // 8192 rows
#define NQK  2048               // QK buffer cols (Q 0..1023, K 1024..2047)
#define QSC  0.18033688f        // 0.125 * log2(e): fold softmax scale + exp2 conversion into Q

typedef __attribute__((ext_vector_type(8))) __bf16 bf16x8;
typedef __attribute__((ext_vector_type(4))) float f32x4;
typedef __attribute__((ext_vector_type(16))) float f32x16;
typedef __attribute__((ext_vector_type(4))) float f4v;
typedef __attribute__((ext_vector_type(4))) unsigned short us4;
typedef __attribute__((ext_vector_type(8))) unsigned short us8;
typedef __attribute__((ext_vector_type(4))) unsigned int u32x4;

static __device__ __forceinline__ unsigned short f2bf(float f) {
  __hip_bfloat16 h = __float2bfloat16(f);
  return __builtin_bit_cast(unsigned short, h);
}

static __device__ __forceinline__ float fast_exp2(float x) {
#if __has_builtin(__builtin_amdgcn_exp2f)
  return __builtin_amdgcn_exp2f(x);
#else
  float r; asm("v_exp_f32 %0, %1" : "=v"(r) : "v"(x)); return r;
#endif
}

static __device__ __forceinline__ void async16(const void* g, void* l) {
  __builtin_amdgcn_global_load_lds(
      (const __attribute__((address_space(1))) void*)g,
      (__attribute__((address_space(3))) void*)l, 16, 0, 0);
}

// cross-half (lane ^ 32) reduce via permlane32_swap (VALU) instead of
// ds_bpermute (__shfl_xor).
#define XHALF(res, x, OP)                                  \
  {                                                        \
    float t1_ = (x), t2_ = (x);                            \
    asm("" : "+v"(t2_));                                   \
    asm("v_permlane32_swap_b32 %0, %1" : "+v"(t1_), "+v"(t2_)); \
    res = OP(t1_, t2_);                                    \
  }
static __device__ __forceinline__ float fadd_(float a, float b) { return a + b; }

// ---------------- fused fp32 -> bf16 convert (x4 vectorized, 1 launch) --------
__global__ __launch_bounds__(256) void cvt_all(
    const float* __restrict__ x, const float* __restrict__ Wq,
    const float* __restrict__ Wk, const float* __restrict__ Wv,
    const float* __restrict__ Wo, unsigned short* __restrict__ xb,
    unsigned short* __restrict__ wqkv, unsigned short* __restrict__ wo) {
  int i = blockIdx.x * blockDim.x + threadIdx.x;
  const float* s; unsigned short* d; int j;
  if (i < 2097152)      { s = x;  d = xb;             j = i; }
  else if (i < 2359296) { s = Wq; d = wqkv;           j = i - 2097152; }
  else if (i < 2621440) { s = Wk; d = wqkv + 1048576; j = i - 2359296; }
  else if (i < 2883584) { s = Wv; d = wqkv + 2097152; j = i - 2621440; }
  else                  { s = Wo; d = wo;             j = i - 2883584; }
  f4v v = reinterpret_cast<const f4v*>(s)[j];
  us4 o;
  o.x = f2bf(v.x); o.y = f2bf(v.y); o.z = f2bf(v.z); o.w = f2bf(v.w);
  reinterpret_cast<us4*>(d)[j] = o;
}

// ---------------- QKV GEMM: BM=128 x BN=256, BK=32 double-buffered -----------
// Attn-style prefetch schedule: { barrier; issue stage(t+1); compute(t) } --
// loads land during the compute phase instead of stalling at the barrier.
// 4-slot XOR swizzle: source gchunk = (t&3)^((t>>3)&3); read slot =
// lg^((lr>>1)&3) -> 2-way bank aliasing (free). 48KB LDS -> 3 blocks/CU.
// Epilogue: QK blocks -> qk[8192][2048] (Q scaled); V blocks -> LDS-staged
// transpose -> coalesced us8 stores to vT[1024][8192].
__global__ __launch_bounds__(512) void gemm_qkv(
    const unsigned short* __restrict__ A,    // [8192][1024] bf16
    const unsigned short* __restrict__ Bw,   // [3072][1024] bf16
    unsigned short* __restrict__ Cqk,        // [8192][2048]
    unsigned short* __restrict__ vT) {       // [1024][8192]
  const int K = 1024;
  // layout (shorts): As0 [0,4096) As1 [4096,8192) Bs0 [8192,16384) Bs1 [16384,24576)
  __shared__ __align__(16) unsigned short Sh[24576];   // 48KB

  const int bid = blockIdx.x;
  const int xcd = bid & 7;
  const int loc = bid >> 3;              // 0..95
  const int m0 = (xcd * 8 + loc / 12) * 128;
  const int n0 = (loc % 12) * 256;

  const int t = threadIdx.x;
  const int lane = t & 63;
  const int w = t >> 6;
  const int lr = lane & 15;
  const int lg = lane >> 4;
  const int wm = w >> 2;                 // 0..1
  const int wn = w & 3;                  // 0..3

  f32x4 acc[4][4];
#pragma unroll
  for (int i = 0; i < 4; ++i)
#pragma unroll
    for (int j = 0; j < 4; ++j) acc[i][j] = (f32x4){0.f, 0.f, 0.f, 0.f};

  // staging: thread t stages LDS chunk t (A), chunks t and 512+t (B).
  // chunk c: row = c>>2, LDS slot = c&3; slot l at row r holds global
  // k-chunk l ^ ((r>>1)&3)  (k-invariant since k0 % 32 == 0).
  const int arow = t >> 2;                        // 0..127
  const int gsA = (t & 3) ^ ((t >> 3) & 3);       // inverse-swizzled source
  const unsigned short* ga  = A + (size_t)(m0 + arow) * K + gsA * 8;
  const unsigned short* gb0 = Bw + (size_t)(n0 + arow) * K + gsA * 8;
  const unsigned short* gb1 = Bw + (size_t)(n0 + 128 + arow) * K + gsA * 8;
  const int rsw = (lr >> 1) & 3;

#define QSTAGE(buf, ko)                                          \
  do {                                                           \
    async16(ga + (ko), &Sh[(buf) * 4096 + t * 8]);               \
    async16(gb0 + (ko), &Sh[8192 + (buf) * 8192 + t * 8]);       \
    async16(gb1 + (ko), &Sh[8192 + (buf) * 8192 + 4096 + t * 8]);\
  } while (0)

  QSTAGE(0, 0);
  int buf = 0;
  for (int k0 = 0; k0 < K; k0 += 32) {
    __syncthreads();                    // buf ready (prefetch had full iter)
    if (k0 + 32 < K) QSTAGE(buf ^ 1, k0 + 32);
    const unsigned short* As = &Sh[buf * 4096];
    const unsigned short* Bs = &Sh[8192 + buf * 8192];
    const int slot = (lg ^ rsw) * 8;
    bf16x8 af[4], bfr[4];
#pragma unroll
    for (int mi = 0; mi < 4; ++mi)
      af[mi] = *(const bf16x8*)&As[(wm * 64 + mi * 16 + lr) * 32 + slot];
#pragma unroll
    for (int ni = 0; ni < 4; ++ni)
      bfr[ni] = *(const bf16x8*)&Bs[(wn * 64 + ni * 16 + lr) * 32 + slot];
#pragma unroll
    for (int mi = 0; mi < 4; ++mi)
#pragma unroll
      for (int ni = 0; ni < 4; ++ni)
        acc[mi][ni] = __builtin_amdgcn_mfma_f32_16x16x32_bf16(
            af[mi], bfr[ni], acc[mi][ni], 0, 0, 0);
    buf ^= 1;
  }
#undef QSTAGE

  // epilogue: D layout col=lane&15, row=(lane>>4)*4+r
  if (n0 < 2048) {
#pragma unroll
    for (int mi = 0; mi < 4; ++mi) {
      const int row = m0 + wm * 64 + mi * 16 + lg * 4;
#pragma unroll
      for (int ni = 0; ni < 4; ++ni) {
        const int col = n0 + wn * 64 + ni * 16 + lr;
        const float sc = (col < 1024) ? QSC : 1.0f;
#pragma unroll
        for (int r = 0; r < 4; ++r)
          Cqk[(size_t)(row + r) * NQK + col] = f2bf(acc[mi][ni][r] * sc);
      }
    }
  } else {
    // V block: LDS-staged transpose, two 128-n halves (Sh free after K-loop).
    __syncthreads();   // all waves done reading Sh before overwrite
#pragma unroll
    for (int hh = 0; hh < 2; ++hh) {
      if ((wn >> 1) == hh) {
        const int nl0 = (wn & 1) * 64;
        const int m = wm * 64 + lg * 4;
#pragma unroll
        for (int mi = 0; mi < 4; ++mi) {
#pragma unroll
          for (int ni = 0; ni < 4; ++ni) {
            const int nl = nl0 + ni * 16 + lr;
            us4 pk;
#pragma unroll
            for (int r = 0; r < 4; ++r) pk[r] = f2bf(acc[mi][ni][r]);
            *(us4*)&Sh[nl * 136 + m + mi * 16] = pk;
          }
        }
      }
      __syncthreads();
      // coalesced store: 4 passes, 16 threads per 256B vT row segment
#pragma unroll
      for (int p = 0; p < 4; ++p) {
        const int flat = p * 512 + t;
        const int row = flat >> 4;          // 0..127 (n within half)
        const int mo = (flat & 15) * 8;     // m offset, shorts
        us8 v = *(const us8*)&Sh[row * 136 + mo];
        *(us8*)&vT[(size_t)(n0 - 2048 + hh * 128 + row) * 8192 + m0 + mo] = v;
      }
      __syncthreads();
    }
  }
}

// ---------------- o-proj GEMM: 128x128, BK=32 double-buffered, f32 + bias ----
template <int NT>
__global__ __launch_bounds__(256) void gemm_bt(
    const unsigned short* __restrict__ A,   // [M][K] bf16 bits
    const unsigned short* __restrict__ Bw,  // [N][K] bf16 bits
    float* __restrict__ Cf,                 // f32 out
    const float* __restrict__ bias,
    int K, int N) {
  __shared__ __align__(16) unsigned short As[2][128 * 32];
  __shared__ __align__(16) unsigned short Bs[2][128 * 32];

  const int bid = blockIdx.x;
  const int xcd = bid & 7;
  const int loc = bid >> 3;
  const int m0 = (xcd * 8 + loc / NT) * 128;
  const int n0 = (loc % NT) * 128;

  const int t = threadIdx.x;
  const int lane = t & 63;
  const int w = t >> 6;
  const int lr = lane & 15;
  const int lg = lane >> 4;
  const int wm = w >> 1;
  const int wn = w & 1;

  f32x4 acc[4][4];
#pragma unroll
  for (int i = 0; i < 4; ++i)
#pragma unroll
    for (int j = 0; j < 4; ++j) acc[i][j] = (f32x4){0.f, 0.f, 0.f, 0.f};

  // chunks c = j*256 + t (j=0,1): row = c>>2, slot = c&3; source k-chunk
  // = (c&3) ^ ((c>>3)&3)  (identical for both j since 256>>3 = 32 ≡ 0 mod 4).
  const int arow = t >> 2;                        // 0..63
  const int gsA = (t & 3) ^ ((t >> 3) & 3);
  const unsigned short* ga = A + (size_t)(m0 + arow) * K + gsA * 8;
  const unsigned short* gb = Bw + (size_t)(n0 + arow) * K + gsA * 8;
  const int rsw = (lr >> 1) & 3;

#define OSTAGE(bufi, ko)                                           \
  do {                                                             \
    async16(ga + (ko), &As[bufi][t * 8]);                          \
    async16(ga + (size_t)64 * K + (ko), &As[bufi][2048 + t * 8]);  \
    async16(gb + (ko), &Bs[bufi][t * 8]);                          \
    async16(gb + (size_t)64 * K + (ko), &Bs[bufi][2048 + t * 8]);  \
  } while (0)

  OSTAGE(0, 0);
  int buf = 0;
  for (int k0 = 0; k0 < K; k0 += 32) {
    __syncthreads();
    if (k0 + 32 < K) OSTAGE(buf ^ 1, k0 + 32);
    const int slot = (lg ^ rsw) * 8;
    bf16x8 af[4], bfr[4];
#pragma unroll
    for (int mi = 0; mi < 4; ++mi)
      af[mi] = *(const bf16x8*)&As[buf][(wm * 64 + mi * 16 + lr) * 32 + slot];
#pragma unroll
    for (int ni = 0; ni < 4; ++ni)
      bfr[ni] = *(const bf16x8*)&Bs[buf][(wn * 64 + ni * 16 + lr) * 32 + slot];
#pragma unroll
    for (int mi = 0; mi < 4; ++mi)
#pragma unroll
      for (int ni = 0; ni < 4; ++ni)
        acc[mi][ni] = __builtin_amdgcn_mfma_f32_16x16x32_bf16(
            af[mi], bfr[ni], acc[mi][ni], 0, 0, 0);
    buf ^= 1;
  }
#undef OSTAGE

#pragma unroll
  for (int mi = 0; mi < 4; ++mi) {
    const int row = m0 + wm * 64 + mi * 16 + lg * 4;
#pragma unroll
    for (int ni = 0; ni < 4; ++ni) {
      const int col = n0 + wn * 64 + ni * 16 + lr;
#pragma unroll
      for (int r = 0; r < 4; ++r)
        Cf[(size_t)(row + r) * N + col] = acc[mi][ni][r] + bias[col];
    }
  }
}

// ---------------- causal flash attention (4 waves x 32 q-rows, 32x32 MFMA) ----
// qk: [8192][2048] bf16 (cols 0..1023 Q pre-scaled, 1024..2047 K)
// vT: [1024][8192] bf16 (row = h*64+d, col = b*T + t)  -> V^T staged via
//     async16 like K (no in-kernel transpose).
// ob: [8192][1024] bf16 attention output (col = h*64+d)
__global__ __launch_bounds__(256, 4) void attn_kernel(
    const unsigned short* __restrict__ qk, const unsigned short* __restrict__ vT,
    unsigned short* __restrict__ ob) {
  const int bid = blockIdx.x;
  const int pair = bid & 63;
  const int g = bid >> 6;               // 0..15, dispatch round-major
  const int rnd = g >> 2, idx = g & 3;
  const int qg = (rnd == 0) ? (15 - idx)
               : (rnd == 1) ? (8 + idx)
               : (rnd == 2) ? (7 - idx) : idx;   // CU sums constant
  const int b = pair >> 4;
  const int h = pair & 15;
  const int t = threadIdx.x;
  const int w = t >> 6;                 // 0..3
  const int lane = t & 63;
  const int l31 = lane & 31;
  const int hi = lane >> 5;

  const int q0w = qg * 128 + w * 32;       // wave's q strip
  const int myBound = 2 * qg + (w >> 1);   // last kv-tile this wave computes
  const int NT = 2 * qg + 2;               // 64-row kv tiles staged by block

  __shared__ __align__(16) unsigned short Ks[2][64 * 64];  // K rows, slot-swz
  __shared__ __align__(16) unsigned short Vs[2][64 * 64];  // V^T rows, slot-swz

  const size_t rowbase = (size_t)(b * T_) * NQK;

  // ---- Q B-fragments: col=q=l31, k=d = m*16 + hi*8 + i ----
  bf16x8 Qf[4];
  {
    const unsigned short* qp =
        qk + rowbase + (size_t)(q0w + l31) * NQK + h * 64 + hi * 8;
#pragma unroll
    for (int m = 0; m < 4; ++m) Qf[m] = *(const bf16x8*)(qp + m * 16);
  }

  // ---- staging geometry (256 threads, 2 async16 each for K and for V^T) ----
  const int kr = t >> 3;                // 0..31 (+32 via second call)
  const int gsw = ((t & 7) ^ (kr & 7)) * 8;
  const unsigned short* kbase =
      qk + rowbase + 1024 + h * 64 + gsw + (size_t)kr * NQK;
  const unsigned short* vbase =
      vT + (size_t)(h * 64 + kr) * 8192 + (size_t)(b * T_) + gsw;

  float m_i = -INFINITY, l_i = 0.f;
  f32x16 o[2];
#pragma unroll
  for (int r = 0; r < 16; ++r) { o[0][r] = 0.f; o[1][r] = 0.f; }

  // ---- prologue: stage tile 0 into buffer 0 ----
  {
    async16(kbase, &Ks[0][t * 8]);
    async16(kbase + (size_t)32 * NQK, &Ks[0][2048 + t * 8]);
    async16(vbase, &Vs[0][t * 8]);
    async16(vbase + (size_t)32 * 8192, &Vs[0][2048 + t * 8]);
  }

  int cur = 0;
  for (int kt = 0; kt < NT; ++kt) {
    __syncthreads();  // buf[cur] ready (vmcnt(0) drains all async16)

    if (kt + 1 < NT) {
      const size_t ko = (size_t)(kt + 1) * 64 * NQK;
      const size_t vo = (size_t)(kt + 1) * 64;
      async16(kbase + ko, &Ks[cur ^ 1][t * 8]);
      async16(kbase + ko + (size_t)32 * NQK, &Ks[cur ^ 1][2048 + t * 8]);
      async16(vbase + vo, &Vs[cur ^ 1][t * 8]);
      async16(vbase + vo + (size_t)32 * 8192, &Vs[cur ^ 1][2048 + t * 8]);
    }

    if (kt <= myBound) {
      const unsigned short* Kb = Ks[cur];
      const unsigned short* Vb = Vs[cur];
      const int r7 = l31 & 7;

      // ---- S^T[kv][q] : 2 kv-subtiles of 32 ----
      f32x16 a0, a1;
#pragma unroll
      for (int r = 0; r < 16; ++r) { a0[r] = 0.f; a1[r] = 0.f; }
      {
        const int rb0 = l31 * 64;
        const int rb1 = (32 + l31) * 64;
        __builtin_amdgcn_s_setprio(1);
#pragma unroll
        for (int m = 0; m < 4; ++m) {
          const int c = (((m << 1) | hi) ^ r7) * 8;
          bf16x8 kf0 = *(const bf16x8*)&Kb[rb0 + c];
          bf16x8 kf1 = *(const bf16x8*)&Kb[rb1 + c];
          a0 = __builtin_amdgcn_mfma_f32_32x32x16_bf16(kf0, Qf[m], a0, 0, 0, 0);
          a1 = __builtin_amdgcn_mfma_f32_32x32x16_bf16(kf1, Qf[m], a1, 0, 0, 0);
        }
        __builtin_amdgcn_s_setprio(0);
      }

      // ---- causal mask: only the diagonal-crossing tile ----
      if (kt == myBound) {
        const int qglob = q0w + l31;
#pragma unroll
        for (int r = 0; r < 16; ++r) {
          const int kvb = kt * 64 + (r & 3) + ((r >> 2) << 3) + (hi << 2);
          if (kvb > qglob) a0[r] = -INFINITY;
          if (kvb + 32 > qglob) a1[r] = -INFINITY;
        }
      }

      // ---- online softmax: tree max, defer-max (THR=8 in log2 space) ----
      float m8[8];
#pragma unroll
      for (int j2 = 0; j2 < 8; ++j2)
        m8[j2] = fmaxf(fmaxf(a0[j2], a0[j2 + 8]), fmaxf(a1[j2], a1[j2 + 8]));
      float pp = fmaxf(fmaxf(fmaxf(m8[0], m8[4]), fmaxf(m8[1], m8[5])),
                       fmaxf(fmaxf(m8[2], m8[6]), fmaxf(m8[3], m8[7])));
      float pmax;
      XHALF(pmax, pp, fmaxf);
      if (__any(pmax > m_i + 8.f)) {
        const float mnew = fmaxf(m_i, pmax);
        const float al = fast_exp2(m_i - mnew);
        m_i = mnew;
        l_i *= al;
#pragma unroll
        for (int r = 0; r < 16; ++r) { o[0][r] *= al; o[1][r] *= al; }
      }

#pragma unroll
      for (int r = 0; r < 16; ++r) {
        a0[r] = fast_exp2(a0[r] - m_i);
        a1[r] = fast_exp2(a1[r] - m_i);
      }
      float s8[8];
#pragma unroll
      for (int j2 = 0; j2 < 8; ++j2)
        s8[j2] = (a0[j2] + a0[j2 + 8]) + (a1[j2] + a1[j2 + 8]);
      float rp = ((s8[0] + s8[1]) + (s8[2] + s8[3])) +
                 ((s8[4] + s8[5]) + (s8[6] + s8[7]));
      float rs;
      XHALF(rs, rp, fadd_);
      l_i += rs;

      // ---- P^T B-fragments: cvt_pk pairs + permlane32_swap half-exchange ----
      bf16x8 Pf[4];
#pragma unroll
      for (int m = 0; m < 4; ++m) {
        const int rb2 = (m & 1) * 8;
        uint32_t u0, u1, u2, u3;
        const f32x16& s = (m >> 1) ? a1 : a0;
        asm("v_cvt_pk_bf16_f32 %0, %1, %2" : "=v"(u0) : "v"(s[rb2 + 0]), "v"(s[rb2 + 1]));
        asm("v_cvt_pk_bf16_f32 %0, %1, %2" : "=v"(u1) : "v"(s[rb2 + 2]), "v"(s[rb2 + 3]));
        asm("v_cvt_pk_bf16_f32 %0, %1, %2" : "=v"(u2) : "v"(s[rb2 + 4]), "v"(s[rb2 + 5]));
        asm("v_cvt_pk_bf16_f32 %0, %1, %2" : "=v"(u3) : "v"(s[rb2 + 6]), "v"(s[rb2 + 7]));
        asm("v_permlane32_swap_b32 %0, %1" : "+v"(u0), "+v"(u2));
        asm("v_permlane32_swap_b32 %0, %1" : "+v"(u1), "+v"(u3));
        u32x4 pw = {u0, u1, u2, u3};
        Pf[m] = __builtin_bit_cast(bf16x8, pw);
      }

      // ---- O^T += V^T P^T  (V^T rows straight from LDS, same swz as K) ----
      __builtin_amdgcn_s_setprio(1);
#pragma unroll
      for (int dt = 0; dt < 2; ++dt) {
        const int base = (dt * 32 + l31) * 64;
#pragma unroll
        for (int m = 0; m < 4; ++m) {
          const int c = (((m << 1) | hi) ^ r7) * 8;
          bf16x8 vf = *(const bf16x8*)&Vb[base + c];
          o[dt] = __builtin_amdgcn_mfma_f32_32x32x16_bf16(vf, Pf[m], o[dt], 0, 0, 0);
        }
      }
      __builtin_amdgcn_s_setprio(0);
    }

    cur ^= 1;
  }

  // ---- epilogue: normalize, pack to bf16, swap to contiguous d-runs, store --
  const float rl = 1.0f / l_i;
#pragma unroll
  for (int dt = 0; dt < 2; ++dt) {
    float s[16];
#pragma unroll
    for (int r = 0; r < 16; ++r) s[r] = o[dt][r] * rl;
    uint32_t u[8];
#pragma unroll
    for (int p = 0; p < 8; ++p)
      asm("v_cvt_pk_bf16_f32 %0, %1, %2" : "=v"(u[p]) : "v"(s[2 * p]), "v"(s[2 * p + 1]));
    asm("v_permlane32_swap_b32 %0, %1" : "+v"(u[0]), "+v"(u[2]));
    asm("v_permlane32_swap_b32 %0, %1" : "+v"(u[1]), "+v"(u[3]));
    asm("v_permlane32_swap_b32 %0, %1" : "+v"(u[4]), "+v"(u[6]));
    asm("v_permlane32_swap_b32 %0, %1" : "+v"(u[5]), "+v"(u[7]));
    unsigned short* op =
        ob + (size_t)(b * T_ + q0w + l31) * 1024 + h * 64 + dt * 32 + hi * 8;
    u32x4 c0 = {u[0], u[1], u[2], u[3]};   // d = dt*32 + hi*8 + [0..8)
    u32x4 c1 = {u[4], u[5], u[6], u[7]};   // d = dt*32 + 16 + hi*8 + [0..8)
    *(u32x4*)op = c0;
    *(u32x4*)(op + 16) = c1;
  }
}

// ---------------- host launch ----------------
extern "C" void kernel_launch(void* const* d_in, const int* in_sizes, int n_in,
                              void* d_out, int out_size, void* d_ws,
                              size_t ws_size, hipStream_t stream) {
  const float* x = (const float*)d_in[0];
  const float* Wq = (const float*)d_in[1];
  const float* Wk = (const float*)d_in[2];
  const float* Wv = (const float*)d_in[3];
  const float* Wo = (const float*)d_in[4];
  const float* bo = (const float*)d_in[5];
  float* out = (float*)d_out;

  char* ws = (char*)d_ws;
  unsigned short* xb   = (unsigned short*)(ws + 0);          // 16 MB
  unsigned short* wqkv = (unsigned short*)(ws + 16777216);   // 6 MB
  unsigned short* wo   = (unsigned short*)(ws + 23068672);   // 2 MB
  unsigned short* qk   = (unsigned short*)(ws + 25165824);   // 32 MB
  unsigned short* vT   = (unsigned short*)(ws + 58720256);   // 16 MB
  unsigned short* ob   = (unsigned short*)(ws + 75497472);   // 16 MB
  if (ws_size < 92274688u) return;

  cvt_all<<<12288, 256, 0, stream>>>(x, Wq, Wk, Wv, Wo, xb, wqkv, wo);

  // fused QKV projection: QK -> qk[8192][2048]; V -> vT[1024][8192] transposed
  gemm_qkv<<<768, 512, 0, stream>>>(xb, wqkv, qk, vT);

  // causal flash attention (V^T async-staged; snake mapping, 4 blocks/CU)
  attn_kernel<<<dim3(1024), 256, 0, stream>>>(qk, vT, ob);

  // output projection + bias
  gemm_bt<8><<<512, 256, 0, stream>>>(ob, wo, out, bo, 1024, 1024);
}

// Round 16
// 152.691 us; speedup vs baseline: 1.1142x; 1.1142x over previous
//
#include <hip/hip_runtime.h>
#include <hip/hip_bf16.h>
#include <stdint.h>

// Problem constants
#define B_   4
#define T_   2048
#define H_   16
#define MTOT (B_ * T_)          // 8192 rows
#define NQK  2048               // QK buffer cols (Q 0..1023, K 1024..2047)
#define QSC  0.18033688f        // 0.125 * log2(e): fold softmax scale + exp2 conversion into Q

typedef __attribute__((ext_vector_type(8))) __bf16 bf16x8;
typedef __attribute__((ext_vector_type(4))) float f32x4;
typedef __attribute__((ext_vector_type(16))) float f32x16;
typedef __attribute__((ext_vector_type(4))) float f4v;
typedef __attribute__((ext_vector_type(4))) unsigned short us4;
typedef __attribute__((ext_vector_type(8))) unsigned short us8;
typedef __attribute__((ext_vector_type(4))) unsigned int u32x4;

static __device__ __forceinline__ unsigned short f2bf(float f) {
  __hip_bfloat16 h = __float2bfloat16(f);
  return __builtin_bit_cast(unsigned short, h);
}

static __device__ __forceinline__ float fast_exp2(float x) {
#if __has_builtin(__builtin_amdgcn_exp2f)
  return __builtin_amdgcn_exp2f(x);
#else
  float r; asm("v_exp_f32 %0, %1" : "=v"(r) : "v"(x)); return r;
#endif
}

static __device__ __forceinline__ void async16(const void* g, void* l) {
  __builtin_amdgcn_global_load_lds(
      (const __attribute__((address_space(1))) void*)g,
      (__attribute__((address_space(3))) void*)l, 16, 0, 0);
}

// cross-half (lane ^ 32) reduce via permlane32_swap (VALU) instead of
// ds_bpermute (__shfl_xor).
#define XHALF(res, x, OP)                                  \
  {                                                        \
    float t1_ = (x), t2_ = (x);                            \
    asm("" : "+v"(t2_));                                   \
    asm("v_permlane32_swap_b32 %0, %1" : "+v"(t1_), "+v"(t2_)); \
    res = OP(t1_, t2_);                                    \
  }
static __device__ __forceinline__ float fadd_(float a, float b) { return a + b; }

// ---------------- fused fp32 -> bf16 convert (x4 vectorized, 1 launch) --------
__global__ __launch_bounds__(256) void cvt_all(
    const float* __restrict__ x, const float* __restrict__ Wq,
    const float* __restrict__ Wk, const float* __restrict__ Wv,
    const float* __restrict__ Wo, unsigned short* __restrict__ xb,
    unsigned short* __restrict__ wqkv, unsigned short* __restrict__ wo) {
  int i = blockIdx.x * blockDim.x + threadIdx.x;
  const float* s; unsigned short* d; int j;
  if (i < 2097152)      { s = x;  d = xb;             j = i; }
  else if (i < 2359296) { s = Wq; d = wqkv;           j = i - 2097152; }
  else if (i < 2621440) { s = Wk; d = wqkv + 1048576; j = i - 2359296; }
  else if (i < 2883584) { s = Wv; d = wqkv + 2097152; j = i - 2621440; }
  else                  { s = Wo; d = wo;             j = i - 2883584; }
  f4v v = reinterpret_cast<const f4v*>(s)[j];
  us4 o;
  o.x = f2bf(v.x); o.y = f2bf(v.y); o.z = f2bf(v.z); o.w = f2bf(v.w);
  reinterpret_cast<us4*>(d)[j] = o;
}

// ---------------- QKV GEMM: BM=128 x BN=256, BK=64, 512 threads --------------
// 2-barrier structure + both-sides K-slot XOR swizzle (proven). Epilogue:
//  - n0 < 2048  (QK blocks): bf16 -> qk[8192][2048], Q cols scaled by QSC.
//  - n0 >= 2048 (V blocks):  transposed via LDS (48KB free after K-loop):
//    stage C^T half-tile [128 n][128 m] in LDS (row stride 136 -> 16B-aligned
//    b128 reads), then fully-coalesced 256B-segment us8 stores to vT[1024][8192].
__global__ __launch_bounds__(512) void gemm_qkv(
    const unsigned short* __restrict__ A,    // [8192][1024] bf16
    const unsigned short* __restrict__ Bw,   // [3072][1024] bf16
    unsigned short* __restrict__ Cqk,        // [8192][2048]
    unsigned short* __restrict__ vT) {       // [1024][8192]
  const int K = 1024;
  __shared__ __align__(16) unsigned short Sh[128 * 64 + 256 * 64];  // 48KB
  unsigned short* const As = Sh;              // [128][64]
  unsigned short* const Bs = Sh + 128 * 64;   // [256][64]

  const int bid = blockIdx.x;
  const int xcd = bid & 7;
  const int loc = bid >> 3;              // 0..95
  const int m0 = (xcd * 8 + loc / 12) * 128;
  const int n0 = (loc % 12) * 256;

  const int t = threadIdx.x;
  const int lane = t & 63;
  const int w = t >> 6;
  const int lr = lane & 15;
  const int lg = lane >> 4;
  const int wm = w >> 2;                 // 0..1
  const int wn = w & 3;                  // 0..3

  f32x4 acc[4][4];
#pragma unroll
  for (int i = 0; i < 4; ++i)
#pragma unroll
    for (int j = 0; j < 4; ++j) acc[i][j] = (f32x4){0.f, 0.f, 0.f, 0.f};

  const int srow = t >> 3;                      // 0..63
  const int gs = (t & 7) ^ (srow & 7);          // inverse-swizzled source slot
  const unsigned short* ga = A + (size_t)(m0 + srow) * K + gs * 8;
  const unsigned short* gb = Bw + (size_t)(n0 + srow) * K + gs * 8;
  const int rsw = lr & 7;

  for (int k0 = 0; k0 < K; k0 += 64) {
#pragma unroll
    for (int k = 0; k < 2; ++k)
      async16(ga + (size_t)(k * 64) * K + k0, &As[(k * 512 + t) * 8]);
#pragma unroll
    for (int k = 0; k < 4; ++k)
      async16(gb + (size_t)(k * 64) * K + k0, &Bs[(k * 512 + t) * 8]);
    __syncthreads();

#pragma unroll
    for (int kk = 0; kk < 2; ++kk) {
      const int slot = ((kk * 4 + lg) ^ rsw) * 8;
      bf16x8 af[4], bfr[4];
#pragma unroll
      for (int mi = 0; mi < 4; ++mi)
        af[mi] = *(const bf16x8*)&As[(wm * 64 + mi * 16 + lr) * 64 + slot];
#pragma unroll
      for (int ni = 0; ni < 4; ++ni)
        bfr[ni] = *(const bf16x8*)&Bs[(wn * 64 + ni * 16 + lr) * 64 + slot];
#pragma unroll
      for (int mi = 0; mi < 4; ++mi)
#pragma unroll
        for (int ni = 0; ni < 4; ++ni)
          acc[mi][ni] = __builtin_amdgcn_mfma_f32_16x16x32_bf16(
              af[mi], bfr[ni], acc[mi][ni], 0, 0, 0);
    }
    __syncthreads();
  }

  // epilogue: D layout col=lane&15, row=(lane>>4)*4+r
  if (n0 < 2048) {
#pragma unroll
    for (int mi = 0; mi < 4; ++mi) {
      const int row = m0 + wm * 64 + mi * 16 + lg * 4;
#pragma unroll
      for (int ni = 0; ni < 4; ++ni) {
        const int col = n0 + wn * 64 + ni * 16 + lr;
        const float sc = (col < 1024) ? QSC : 1.0f;
#pragma unroll
        for (int r = 0; r < 4; ++r)
          Cqk[(size_t)(row + r) * NQK + col] = f2bf(acc[mi][ni][r] * sc);
      }
    }
  } else {
    // V block: LDS-staged transpose, two 128-n halves. Sh free after K-loop.
#pragma unroll
    for (int hh = 0; hh < 2; ++hh) {
      if ((wn >> 1) == hh) {
        const int nl0 = (wn & 1) * 64;
        const int m = wm * 64 + lg * 4;
#pragma unroll
        for (int mi = 0; mi < 4; ++mi) {
#pragma unroll
          for (int ni = 0; ni < 4; ++ni) {
            const int nl = nl0 + ni * 16 + lr;
            us4 pk;
#pragma unroll
            for (int r = 0; r < 4; ++r) pk[r] = f2bf(acc[mi][ni][r]);
            *(us4*)&Sh[nl * 136 + m + mi * 16] = pk;
          }
        }
      }
      __syncthreads();
      // coalesced store: 4 passes, 16 threads per 256B vT row segment
#pragma unroll
      for (int p = 0; p < 4; ++p) {
        const int flat = p * 512 + t;
        const int row = flat >> 4;          // 0..127 (n within half)
        const int mo = (flat & 15) * 8;     // m offset, shorts
        us8 v = *(const us8*)&Sh[row * 136 + mo];
        *(us8*)&vT[(size_t)(n0 - 2048 + hh * 128 + row) * 8192 + m0 + mo] = v;
      }
      __syncthreads();
    }
  }
}

// ---------------- bf16 GEMM (2-barrier, BK=64), o-proj: f32 out + bias -------
template <int NT>
__global__ __launch_bounds__(256) void gemm_bt(
    const unsigned short* __restrict__ A,   // [M][K] bf16 bits
    const unsigned short* __restrict__ Bw,  // [N][K] bf16 bits
    float* __restrict__ Cf,                 // f32 out
    const float* __restrict__ bias,
    int K, int N) {
  __shared__ __align__(16) unsigned short As[128 * 64];
  __shared__ __align__(16) unsigned short Bs[128 * 64];

  const int bid = blockIdx.x;
  const int xcd = bid & 7;
  const int loc = bid >> 3;
  const int m0 = (xcd * 8 + loc / NT) * 128;
  const int n0 = (loc % NT) * 128;

  const int t = threadIdx.x;
  const int lane = t & 63;
  const int w = t >> 6;
  const int lr = lane & 15;
  const int lg = lane >> 4;
  const int wm = w >> 1;
  const int wn = w & 1;

  f32x4 acc[4][4];
#pragma unroll
  for (int i = 0; i < 4; ++i)
#pragma unroll
    for (int j = 0; j < 4; ++j) acc[i][j] = (f32x4){0.f, 0.f, 0.f, 0.f};

  const int srow = t >> 3;
  const int gs = (t & 7) ^ ((t >> 3) & 7);
  const unsigned short* ga = A + (size_t)(m0 + srow) * K + gs * 8;
  const unsigned short* gb = Bw + (size_t)(n0 + srow) * K + gs * 8;

  const int rsw = lr & 7;

  for (int k0 = 0; k0 < K; k0 += 64) {
#pragma unroll
    for (int k = 0; k < 4; ++k) {
      async16(ga + (size_t)(k * 32) * K + k0, &As[(k * 256 + t) * 8]);
      async16(gb + (size_t)(k * 32) * K + k0, &Bs[(k * 256 + t) * 8]);
    }
    __syncthreads();

#pragma unroll
    for (int kk = 0; kk < 2; ++kk) {
      const int slot = ((kk * 4 + lg) ^ rsw) * 8;
      bf16x8 af[4], bfr[4];
#pragma unroll
      for (int mi = 0; mi < 4; ++mi)
        af[mi] = *(const bf16x8*)&As[(wm * 64 + mi * 16 + lr) * 64 + slot];
#pragma unroll
      for (int ni = 0; ni < 4; ++ni)
        bfr[ni] = *(const bf16x8*)&Bs[(wn * 64 + ni * 16 + lr) * 64 + slot];
#pragma unroll
      for (int mi = 0; mi < 4; ++mi)
#pragma unroll
        for (int ni = 0; ni < 4; ++ni)
          acc[mi][ni] = __builtin_amdgcn_mfma_f32_16x16x32_bf16(
              af[mi], bfr[ni], acc[mi][ni], 0, 0, 0);
    }
    __syncthreads();
  }

#pragma unroll
  for (int mi = 0; mi < 4; ++mi) {
    const int row = m0 + wm * 64 + mi * 16 + lg * 4;
#pragma unroll
    for (int ni = 0; ni < 4; ++ni) {
      const int col = n0 + wn * 64 + ni * 16 + lr;
#pragma unroll
      for (int r = 0; r < 4; ++r)
        Cf[(size_t)(row + r) * N + col] = acc[mi][ni][r] + bias[col];
    }
  }
}

// ---------------- causal flash attention (4 waves x 32 q-rows, 32x32 MFMA) ----
// qk: [8192][2048] bf16 (cols 0..1023 Q pre-scaled, 1024..2047 K)
// vT: [1024][8192] bf16 (row = h*64+d, col = b*T + t)  -> V^T staged via
//     async16 like K (no in-kernel transpose).
// ob: [8192][1024] bf16 attention output (col = h*64+d)
__global__ __launch_bounds__(256, 4) void attn_kernel(
    const unsigned short* __restrict__ qk, const unsigned short* __restrict__ vT,
    unsigned short* __restrict__ ob) {
  const int bid = blockIdx.x;
  const int pair = bid & 63;
  const int g = bid >> 6;               // 0..15, dispatch round-major
  const int rnd = g >> 2, idx = g & 3;
  const int qg = (rnd == 0) ? (15 - idx)
               : (rnd == 1) ? (8 + idx)
               : (rnd == 2) ? (7 - idx) : idx;   // CU sums constant
  const int b = pair >> 4;
  const int h = pair & 15;
  const int t = threadIdx.x;
  const int w = t >> 6;                 // 0..3
  const int lane = t & 63;
  const int l31 = lane & 31;
  const int hi = lane >> 5;

  const int q0w = qg * 128 + w * 32;       // wave's q strip
  const int myBound = 2 * qg + (w >> 1);   // last kv-tile this wave computes
  const int NT = 2 * qg + 2;               // 64-row kv tiles staged by block

  __shared__ __align__(16) unsigned short Ks[2][64 * 64];  // K rows, slot-swz
  __shared__ __align__(16) unsigned short Vs[2][64 * 64];  // V^T rows, slot-swz

  const size_t rowbase = (size_t)(b * T_) * NQK;

  // ---- Q B-fragments: col=q=l31, k=d = m*16 + hi*8 + i ----
  bf16x8 Qf[4];
  {
    const unsigned short* qp =
        qk + rowbase + (size_t)(q0w + l31) * NQK + h * 64 + hi * 8;
#pragma unroll
    for (int m = 0; m < 4; ++m) Qf[m] = *(const bf16x8*)(qp + m * 16);
  }

  // ---- staging geometry (256 threads, 2 async16 each for K and for V^T) ----
  const int kr = t >> 3;                // 0..31 (+32 via second call)
  const int gsw = ((t & 7) ^ (kr & 7)) * 8;
  const unsigned short* kbase =
      qk + rowbase + 1024 + h * 64 + gsw + (size_t)kr * NQK;
  const unsigned short* vbase =
      vT + (size_t)(h * 64 + kr) * 8192 + (size_t)(b * T_) + gsw;

  float m_i = -INFINITY, l_i = 0.f;
  f32x16 o[2];
#pragma unroll
  for (int r = 0; r < 16; ++r) { o[0][r] = 0.f; o[1][r] = 0.f; }

  // ---- prologue: stage tile 0 into buffer 0 ----
  {
    async16(kbase, &Ks[0][t * 8]);
    async16(kbase + (size_t)32 * NQK, &Ks[0][2048 + t * 8]);
    async16(vbase, &Vs[0][t * 8]);
    async16(vbase + (size_t)32 * 8192, &Vs[0][2048 + t * 8]);
  }

  int cur = 0;
  for (int kt = 0; kt < NT; ++kt) {
    __syncthreads();  // buf[cur] ready (vmcnt(0) drains all async16)

    if (kt + 1 < NT) {
      const size_t ko = (size_t)(kt + 1) * 64 * NQK;
      const size_t vo = (size_t)(kt + 1) * 64;
      async16(kbase + ko, &Ks[cur ^ 1][t * 8]);
      async16(kbase + ko + (size_t)32 * NQK, &Ks[cur ^ 1][2048 + t * 8]);
      async16(vbase + vo, &Vs[cur ^ 1][t * 8]);
      async16(vbase + vo + (size_t)32 * 8192, &Vs[cur ^ 1][2048 + t * 8]);
    }

    if (kt <= myBound) {
      const unsigned short* Kb = Ks[cur];
      const unsigned short* Vb = Vs[cur];
      const int r7 = l31 & 7;

      // ---- S^T[kv][q] : 2 kv-subtiles of 32 ----
      f32x16 a0, a1;
#pragma unroll
      for (int r = 0; r < 16; ++r) { a0[r] = 0.f; a1[r] = 0.f; }
      {
        const int rb0 = l31 * 64;
        const int rb1 = (32 + l31) * 64;
        __builtin_amdgcn_s_setprio(1);
#pragma unroll
        for (int m = 0; m < 4; ++m) {
          const int c = (((m << 1) | hi) ^ r7) * 8;
          bf16x8 kf0 = *(const bf16x8*)&Kb[rb0 + c];
          bf16x8 kf1 = *(const bf16x8*)&Kb[rb1 + c];
          a0 = __builtin_amdgcn_mfma_f32_32x32x16_bf16(kf0, Qf[m], a0, 0, 0, 0);
          a1 = __builtin_amdgcn_mfma_f32_32x32x16_bf16(kf1, Qf[m], a1, 0, 0, 0);
        }
        __builtin_amdgcn_s_setprio(0);
      }

      // ---- causal mask: only the diagonal-crossing tile ----
      if (kt == myBound) {
        const int qglob = q0w + l31;
#pragma unroll
        for (int r = 0; r < 16; ++r) {
          const int kvb = kt * 64 + (r & 3) + ((r >> 2) << 3) + (hi << 2);
          if (kvb > qglob) a0[r] = -INFINITY;
          if (kvb + 32 > qglob) a1[r] = -INFINITY;
        }
      }

      // ---- online softmax: tree max, defer-max (THR=8 in log2 space) ----
      float m8[8];
#pragma unroll
      for (int j2 = 0; j2 < 8; ++j2)
        m8[j2] = fmaxf(fmaxf(a0[j2], a0[j2 + 8]), fmaxf(a1[j2], a1[j2 + 8]));
      float pp = fmaxf(fmaxf(fmaxf(m8[0], m8[4]), fmaxf(m8[1], m8[5])),
                       fmaxf(fmaxf(m8[2], m8[6]), fmaxf(m8[3], m8[7])));
      float pmax;
      XHALF(pmax, pp, fmaxf);
      if (__any(pmax > m_i + 8.f)) {
        const float mnew = fmaxf(m_i, pmax);
        const float al = fast_exp2(m_i - mnew);
        m_i = mnew;
        l_i *= al;
#pragma unroll
        for (int r = 0; r < 16; ++r) { o[0][r] *= al; o[1][r] *= al; }
      }

#pragma unroll
      for (int r = 0; r < 16; ++r) {
        a0[r] = fast_exp2(a0[r] - m_i);
        a1[r] = fast_exp2(a1[r] - m_i);
      }
      float s8[8];
#pragma unroll
      for (int j2 = 0; j2 < 8; ++j2)
        s8[j2] = (a0[j2] + a0[j2 + 8]) + (a1[j2] + a1[j2 + 8]);
      float rp = ((s8[0] + s8[1]) + (s8[2] + s8[3])) +
                 ((s8[4] + s8[5]) + (s8[6] + s8[7]));
      float rs;
      XHALF(rs, rp, fadd_);
      l_i += rs;

      // ---- P^T B-fragments: cvt_pk pairs + permlane32_swap half-exchange ----
      bf16x8 Pf[4];
#pragma unroll
      for (int m = 0; m < 4; ++m) {
        const int rb2 = (m & 1) * 8;
        uint32_t u0, u1, u2, u3;
        const f32x16& s = (m >> 1) ? a1 : a0;
        asm("v_cvt_pk_bf16_f32 %0, %1, %2" : "=v"(u0) : "v"(s[rb2 + 0]), "v"(s[rb2 + 1]));
        asm("v_cvt_pk_bf16_f32 %0, %1, %2" : "=v"(u1) : "v"(s[rb2 + 2]), "v"(s[rb2 + 3]));
        asm("v_cvt_pk_bf16_f32 %0, %1, %2" : "=v"(u2) : "v"(s[rb2 + 4]), "v"(s[rb2 + 5]));
        asm("v_cvt_pk_bf16_f32 %0, %1, %2" : "=v"(u3) : "v"(s[rb2 + 6]), "v"(s[rb2 + 7]));
        asm("v_permlane32_swap_b32 %0, %1" : "+v"(u0), "+v"(u2));
        asm("v_permlane32_swap_b32 %0, %1" : "+v"(u1), "+v"(u3));
        u32x4 pw = {u0, u1, u2, u3};
        Pf[m] = __builtin_bit_cast(bf16x8, pw);
      }

      // ---- O^T += V^T P^T  (V^T rows straight from LDS, same swz as K) ----
      __builtin_amdgcn_s_setprio(1);
#pragma unroll
      for (int dt = 0; dt < 2; ++dt) {
        const int base = (dt * 32 + l31) * 64;
#pragma unroll
        for (int m = 0; m < 4; ++m) {
          const int c = (((m << 1) | hi) ^ r7) * 8;
          bf16x8 vf = *(const bf16x8*)&Vb[base + c];
          o[dt] = __builtin_amdgcn_mfma_f32_32x32x16_bf16(vf, Pf[m], o[dt], 0, 0, 0);
        }
      }
      __builtin_amdgcn_s_setprio(0);
    }

    cur ^= 1;
  }

  // ---- epilogue: normalize, pack to bf16, swap to contiguous d-runs, store --
  const float rl = 1.0f / l_i;
#pragma unroll
  for (int dt = 0; dt < 2; ++dt) {
    float s[16];
#pragma unroll
    for (int r = 0; r < 16; ++r) s[r] = o[dt][r] * rl;
    uint32_t u[8];
#pragma unroll
    for (int p = 0; p < 8; ++p)
      asm("v_cvt_pk_bf16_f32 %0, %1, %2" : "=v"(u[p]) : "v"(s[2 * p]), "v"(s[2 * p + 1]));
    asm("v_permlane32_swap_b32 %0, %1" : "+v"(u[0]), "+v"(u[2]));
    asm("v_permlane32_swap_b32 %0, %1" : "+v"(u[1]), "+v"(u[3]));
    asm("v_permlane32_swap_b32 %0, %1" : "+v"(u[4]), "+v"(u[6]));
    asm("v_permlane32_swap_b32 %0, %1" : "+v"(u[5]), "+v"(u[7]));
    unsigned short* op =
        ob + (size_t)(b * T_ + q0w + l31) * 1024 + h * 64 + dt * 32 + hi * 8;
    u32x4 c0 = {u[0], u[1], u[2], u[3]};   // d = dt*32 + hi*8 + [0..8)
    u32x4 c1 = {u[4], u[5], u[6], u[7]};   // d = dt*32 + 16 + hi*8 + [0..8)
    *(u32x4*)op = c0;
    *(u32x4*)(op + 16) = c1;
  }
}

// ---------------- host launch ----------------
extern "C" void kernel_launch(void* const* d_in, const int* in_sizes, int n_in,
                              void* d_out, int out_size, void* d_ws,
                              size_t ws_size, hipStream_t stream) {
  const float* x = (const float*)d_in[0];
  const float* Wq = (const float*)d_in[1];
  const float* Wk = (const float*)d_in[2];
  const float* Wv = (const float*)d_in[3];
  const float* Wo = (const float*)d_in[4];
  const float* bo = (const float*)d_in[5];
  float* out = (float*)d_out;

  char* ws = (char*)d_ws;
  unsigned short* xb   = (unsigned short*)(ws + 0);          // 16 MB
  unsigned short* wqkv = (unsigned short*)(ws + 16777216);   // 6 MB
  unsigned short* wo   = (unsigned short*)(ws + 23068672);   // 2 MB
  unsigned short* qk   = (unsigned short*)(ws + 25165824);   // 32 MB
  unsigned short* vT   = (unsigned short*)(ws + 58720256);   // 16 MB
  unsigned short* ob   = (unsigned short*)(ws + 75497472);   // 16 MB
  if (ws_size < 92274688u) return;

  cvt_all<<<12288, 256, 0, stream>>>(x, Wq, Wk, Wv, Wo, xb, wqkv, wo);

  // fused QKV projection: QK -> qk[8192][2048]; V -> vT[1024][8192] transposed
  gemm_qkv<<<768, 512, 0, stream>>>(xb, wqkv, qk, vT);

  // causal flash attention (V^T async-staged; snake mapping, 4 blocks/CU)
  attn_kernel<<<dim3(1024), 256, 0, stream>>>(qk, vT, ob);

  // output projection + bias
  gemm_bt<8><<<512, 256, 0, stream>>>(ob, wo, out, bo, 1024, 1024);
}